// Round 5
// baseline (182.874 us; speedup 1.0000x reference)
//
#include <hip/hip_runtime.h>
#include <hip/hip_bf16.h>

// Problem constants (NoiseEfficientNet): B=32, Cin=96, Cout=144, H=W=56, 3x3 pad1
#define B_    32
#define CIN   96
#define COUT  144
#define H_    56
#define W_    56
#define HW    3136      // 56*56
#define NPIX  100352    // 32*3136
#define KTOT  864       // 9 taps * 96 ci
#define MT    256       // workgroup pixel tile (4 waves x 64 pixels each)
#define TAPSZ (COUT*CIN) // 13824 shorts per tap in Wt2
#define GRP   1536       // shorts per 16-pixel fragment group (16*96)

typedef short  short8  __attribute__((ext_vector_type(8)));
typedef float  floatx4 __attribute__((ext_vector_type(4)));

// 16B of guaranteed zeros for halo-fragment redirection (zero-init at load)
__device__ __attribute__((aligned(64))) float g_zero[16];

__device__ __forceinline__ unsigned short f2bf(float f) {
    union { float f; unsigned int u; } v; v.f = f;
    unsigned int u = v.u;
    return (unsigned short)((u + 0x7FFFu + ((u >> 16) & 1u)) >> 16);  // RNE
}

// async global->LDS, 16B per lane; LDS dest is wave-uniform base + lane*16
__device__ __forceinline__ void glds16(const void* g, void* l) {
    __builtin_amdgcn_global_load_lds(
        (const __attribute__((address_space(1))) unsigned int*)g,
        (__attribute__((address_space(3))) unsigned int*)l, 16, 0, 0);
}

// ---------------------------------------------------------------------------
// Fused prep kernel.
//   transpose: x [B][96][56][56] f32 -> xA fragment-major bf16:
//       xA[p>>4][ks][q][p&15][j]  (j<8, ci = ks*32+q*8+j) — a wave's A-frag
//       b128 load covers ~8 contiguous runs instead of a 64-line scatter.
//   weights:   Wm [144][96][3][3] f32 -> Wt2 [tap][g][co][8] bf16 (granule-
//       major: consecutive co = consecutive 16B -> coalesced glds).
//   E table:   E [B][144][3][3] f32 (boundary-class constants, extra path)
// ---------------------------------------------------------------------------
#define TB 1568
#define WB 486
__global__ __launch_bounds__(256) void prep_all(const float* __restrict__ x,
                                                unsigned short* __restrict__ xA,
                                                const float* __restrict__ Wm,
                                                unsigned short* __restrict__ Wt2,
                                                const float* __restrict__ extra,
                                                const float* __restrict__ Wx,
                                                const float* __restrict__ bm,
                                                const float* __restrict__ bx,
                                                float* __restrict__ E) {
    __shared__ __align__(16) unsigned short tile[64][CIN + 8];
    int blk = blockIdx.x;
    int t = threadIdx.x;
    if (blk < TB) {
        int b   = blk / 49;
        int hw0 = (blk % 49) * 64;
        const float* xb = x + (size_t)b * CIN * HW;
        for (int i = t; i < CIN * 16; i += 256) {
            int ci = i >> 4, seg = i & 15;
            float4 v = *(const float4*)(xb + (size_t)ci * HW + hw0 + seg * 4);
            int hwl = seg * 4;
            tile[hwl + 0][ci] = f2bf(v.x);
            tile[hwl + 1][ci] = f2bf(v.y);
            tile[hwl + 2][ci] = f2bf(v.z);
            tile[hwl + 3][ci] = f2bf(v.w);
        }
        __syncthreads();
        // write 768 16B chunks: c = ((t_local*3 + ks)*4 + q)*16 + r
        int g0 = (b * HW + hw0) >> 4;             // Pbase/16 (hw0 % 64 == 0)
        #pragma unroll
        for (int jj = 0; jj < 3; ++jj) {
            int c = t + jj * 256;
            int r = c & 15;
            int y = c >> 4;
            int qq = y & 3;
            int z = y >> 2;                        // t_local*3 + ks
            int ks = z % 3, tl = z / 3;
            const uint4* s = (const uint4*)&tile[tl * 16 + r][ks * 32 + qq * 8];
            uint4* d = (uint4*)(xA + (size_t)(g0 + tl) * GRP + ks * 512 + qq * 128 + r * 8);
            *d = *s;
        }
    } else if (blk < TB + WB) {
        int i = (blk - TB) * 256 + t;      // [0, 124416)
        int tap = i / TAPSZ;
        int rem = i - tap * TAPSZ;
        int g   = rem / (COUT * 8);
        int rr  = rem - g * (COUT * 8);
        int co  = rr >> 3, j = rr & 7;
        int ci  = g * 8 + j;
        Wt2[i] = f2bf(Wm[((size_t)co * CIN + ci) * 9 + tap]);
    } else {
        int i = (blk - TB - WB) * 256 + t; // [0, 4608)
        int b = i / COUT, co = i - b * COUT;
        float base = bm[co] + bx[co];
        float m[3][3] = {{0,0,0},{0,0,0},{0,0,0}};
        for (int f = 0; f < 3; ++f) {
            float e = extra[(size_t)b * (COUT * 3) + co * 3 + f];
            const float* w = Wx + ((size_t)co * 3 + f) * 9;
            for (int rc = 0; rc < 3; ++rc) {
                int kh0 = (rc == 0) ? 1 : 0;
                int kh1 = (rc == 2) ? 1 : 2;
                for (int cc = 0; cc < 3; ++cc) {
                    int kw0 = (cc == 0) ? 1 : 0;
                    int kw1 = (cc == 2) ? 1 : 2;
                    float s = 0.f;
                    for (int kh = kh0; kh <= kh1; ++kh)
                        for (int kw = kw0; kw <= kw1; ++kw)
                            s += w[kh * 3 + kw];
                    m[rc][cc] += e * s;
                }
            }
        }
        float* dst = E + (size_t)i * 9;
        for (int rc = 0; rc < 3; ++rc)
            for (int cc = 0; cc < 3; ++cc)
                dst[rc * 3 + cc] = base + m[rc][cc];
    }
}

// ---------------------------------------------------------------------------
// Main implicit GEMM v3.
// Block: 256 thr = 4 waves; tile 256 px x 144 co; wave = 64 px x 144 co.
// A: direct global->VGPR from fragment-major xA (near-contiguous b128 loads);
//    a01[ms][ks<2] single-buffered (refilled right after last use per ks),
//    a2[parity][ms] double-buffered (prefetched a full tap early).
// B: LDS double-buffer [g][co] via coalesced glds from granule-major Wt2.
// Register budget: acc 144 AGPR + ~110 VGPR -> __launch_bounds__(256,2)
// gives 2 blocks/CU so one block's barrier drain overlaps the other's MFMAs.
// ---------------------------------------------------------------------------
__global__ __launch_bounds__(256, 2) void conv_gemm(const unsigned short* __restrict__ xA,
                                                    const unsigned short* __restrict__ Wt2,
                                                    const float* __restrict__ E,
                                                    float* __restrict__ out) {
    __shared__ __align__(16) unsigned short Bs[2 * TAPSZ];   // 2 x 27648 B

    int tid = threadIdx.x;
    int wv = tid >> 6, lane = tid & 63;
    int r16 = lane & 15, q = lane >> 4;
    int pixBase = blockIdx.x * MT;

    floatx4 acc[4][9];
    #pragma unroll
    for (int m = 0; m < 4; ++m)
        #pragma unroll
        for (int n = 0; n < 9; ++n)
            acc[m][n] = (floatx4){0.f, 0.f, 0.f, 0.f};

    // ---- A addressing (per ms-subtile, tap-invariant) ----
    int pms[4], hA[4], wA[4];
    #pragma unroll
    for (int ms = 0; ms < 4; ++ms) {
        int p = pixBase + wv * 64 + ms * 16 + r16;   // A-frag m = lane&15
        pms[ms] = p;
        int hw = p % HW;
        hA[ms] = hw / W_;
        wA[ms] = hw - hA[ms] * W_;
    }
    const unsigned short* gz = (const unsigned short*)g_zero;

    // ---- B staging: slot s = tid + j*256 -> (g = s/144, co = s%144);
    //      Wt2 granule-major => consecutive tid = contiguous 16B (coalesced)
    int bSrc[7];
    #pragma unroll
    for (int j = 0; j < 7; ++j) {
        int s = tid + j * 256;
        int g = s / COUT, co = s - g * COUT;
        bSrc[j] = g * (COUT * 8) + co * 8;
    }
    const bool bTail = (tid < 192);   // waves 0-2 stage slots [1536,1728)

    // B-frag LDS read base (shorts): addr(n,ks) = base + ks*4608 + n*128
    const unsigned short* BpBase = Bs + (q * COUT + r16) * 8;

    short8 a01[4][2];   // ks=0,1 current tap (single-buffered)
    short8 a2[2][4];    // ks=2, double-buffered by tap parity

// A-frag load: pixel p = pms[ms]+off, fragment-major address; halo -> g_zero
#define ALOAD(dst, ms, ks, dh, dw, off)                                         \
    {                                                                           \
        int p_ = pms[ms] + (off);                                               \
        bool v_ = ((unsigned)(hA[ms] + (dh)) < H_) &&                           \
                  ((unsigned)(wA[ms] + (dw)) < W_);                             \
        const unsigned short* ptr_ = v_                                         \
            ? (xA + (long)(p_ >> 4) * GRP + (p_ & 15) * 8 + q * 128 + (ks) * 512)\
            : gz;                                                               \
        dst = *(const short8*)ptr_;                                             \
    }

#define STAGE_B(tap_, bd_)                                                      \
    {                                                                           \
        const unsigned short* wsrc_ = Wt2 + (tap_) * TAPSZ;                     \
        _Pragma("unroll")                                                       \
        for (int j = 0; j < 6; ++j)                                             \
            glds16(wsrc_ + bSrc[j], (void*)((bd_) + tid * 8 + j * 2048));       \
        if (bTail)                                                              \
            glds16(wsrc_ + bSrc[6], (void*)((bd_) + tid * 8 + 6 * 2048));       \
    }

    // ---- prologue: tap 0 (dh=-1, dw=-1, off=-57) ----
    STAGE_B(0, Bs);
    #pragma unroll
    for (int ms = 0; ms < 4; ++ms) {
        ALOAD(a01[ms][0], ms, 0, -1, -1, -57);
        ALOAD(a01[ms][1], ms, 1, -1, -1, -57);
        ALOAD(a2[0][ms],  ms, 2, -1, -1, -57);
    }
    __syncthreads();   // tap 0 B in LDS, A in regs

    #pragma unroll
    for (int tap = 0; tap < 9; ++tap) {
        const int cur = tap & 1, nxt = cur ^ 1;
        const int tap2 = tap + 1;
        const int dh2 = tap2 / 3 - 1, dw2 = tap2 - (tap2 / 3) * 3 - 1;
        const int off2 = dh2 * W_ + dw2;
        const unsigned short* Bp = BpBase + cur * TAPSZ;

        // next tap's B staging + ks=2 A prefetch (full compute phase to land)
        if (tap < 8) {
            STAGE_B(tap2, Bs + nxt * TAPSZ);
            #pragma unroll
            for (int ms = 0; ms < 4; ++ms)
                ALOAD(a2[nxt][ms], ms, 2, dh2, dw2, off2);
        }

        // ---- ks = 0 ----
        #pragma unroll
        for (int n = 0; n < 9; ++n) {
            short8 bfv = *(const short8*)(Bp + n * 128);
            #pragma unroll
            for (int ms = 0; ms < 4; ++ms)
                acc[ms][n] = __builtin_amdgcn_mfma_f32_16x16x32_bf16(
                    a01[ms][0], bfv, acc[ms][n], 0, 0, 0);
        }
        if (tap < 8) {   // a01[.][0] dead -> refill for next tap (2/3-tap cover)
            #pragma unroll
            for (int ms = 0; ms < 4; ++ms)
                ALOAD(a01[ms][0], ms, 0, dh2, dw2, off2);
        }

        // ---- ks = 1 ----
        #pragma unroll
        for (int n = 0; n < 9; ++n) {
            short8 bfv = *(const short8*)(Bp + 4608 + n * 128);
            #pragma unroll
            for (int ms = 0; ms < 4; ++ms)
                acc[ms][n] = __builtin_amdgcn_mfma_f32_16x16x32_bf16(
                    a01[ms][1], bfv, acc[ms][n], 0, 0, 0);
        }
        if (tap < 8) {   // a01[.][1] dead -> refill (1/3-tap cover)
            #pragma unroll
            for (int ms = 0; ms < 4; ++ms)
                ALOAD(a01[ms][1], ms, 1, dh2, dw2, off2);
        }

        // ---- ks = 2 (double-buffered regs) ----
        #pragma unroll
        for (int n = 0; n < 9; ++n) {
            short8 bfv = *(const short8*)(Bp + 2 * 4608 + n * 128);
            #pragma unroll
            for (int ms = 0; ms < 4; ++ms)
                acc[ms][n] = __builtin_amdgcn_mfma_f32_16x16x32_bf16(
                    a2[cur][ms], bfv, acc[ms][n], 0, 0, 0);
        }

        // drain next tap's glds + release cur B buffer
        __syncthreads();
    }

    // ---- epilogue: direct stores, out = acc + E[b][co][rc(h)][cc(w)] ----
    #pragma unroll
    for (int ms = 0; ms < 4; ++ms) {
        int p0 = pixBase + wv * 64 + ms * 16 + q * 4;  // D-layout row = q*4+reg
        int b  = p0 / HW;
        int hw0 = p0 - b * HW;                          // 4-aligned, no b straddle
        int h = hw0 / W_;
        int w0 = hw0 - h * W_;                          // 4-aligned, no row straddle
        int rc = (h == 0) ? 0 : ((h == H_ - 1) ? 2 : 1);
        int cc0 = (w0 == 0) ? 0 : ((w0 == W_ - 1) ? 2 : 1);
        int cc1 = (w0 + 1 == W_ - 1) ? 2 : 1;
        int cc2 = (w0 + 2 == W_ - 1) ? 2 : 1;
        int cc3 = (w0 + 3 == W_ - 1) ? 2 : 1;
        const float* Ebase = E + (size_t)b * COUT * 9 + rc * 3;
        float* outB = out + (size_t)b * COUT * HW + hw0;
        #pragma unroll
        for (int n = 0; n < 9; ++n) {
            int co = n * 16 + r16;                      // D-layout col = lane&15
            const float* Eb = Ebase + co * 9;
            float4 v;
            v.x = acc[ms][n][0] + Eb[cc0];
            v.y = acc[ms][n][1] + Eb[cc1];
            v.z = acc[ms][n][2] + Eb[cc2];
            v.w = acc[ms][n][3] + Eb[cc3];
            *(float4*)(outB + (size_t)co * HW) = v;
        }
    }
#undef ALOAD
#undef STAGE_B
}

// ---------------------------------------------------------------------------
extern "C" void kernel_launch(void* const* d_in, const int* in_sizes, int n_in,
                              void* d_out, int out_size, void* d_ws, size_t ws_size,
                              hipStream_t stream) {
    const float* x     = (const float*)d_in[0];
    const float* extra = (const float*)d_in[1];
    const float* Wm    = (const float*)d_in[2];
    const float* bm    = (const float*)d_in[3];
    const float* Wx    = (const float*)d_in[4];
    const float* bx    = (const float*)d_in[5];
    float* out = (float*)d_out;

    const size_t XA_BYTES = (size_t)NPIX * CIN * 2;    // 19,267,584
    const size_t WT_BYTES = (size_t)COUT * KTOT * 2;   //    248,832
    const size_t E_BYTES  = (size_t)B_ * COUT * 9 * 4; //    165,888
    if (ws_size < XA_BYTES + WT_BYTES + E_BYTES) return;

    unsigned short* xA  = (unsigned short*)d_ws;
    unsigned short* Wt2 = (unsigned short*)((char*)d_ws + XA_BYTES);
    float*          E   = (float*)((char*)d_ws + XA_BYTES + WT_BYTES);

    prep_all<<<TB + WB + 18, 256, 0, stream>>>(x, xA, Wm, Wt2, extra, Wx, bm, bx, E);
    conv_gemm<<<NPIX / MT, 256, 0, stream>>>(xA, Wt2, E, out);
}